// Round 6
// baseline (187.625 us; speedup 1.0000x reference)
//
#include <hip/hip_runtime.h>

typedef __bf16 bf16x8 __attribute__((ext_vector_type(8)));
typedef __bf16 bf16x4 __attribute__((ext_vector_type(4)));
typedef float f32x4 __attribute__((ext_vector_type(4)));

#define B_TOT   16384
#define DM      512
#define NF      64
#define KU      64   // K for final GEMM: 8 G + 36 sym pairs + 1 eye + 19 zero

#define MFMA16(a,b,c) __builtin_amdgcn_mfma_f32_16x16x32_bf16(a,b,c,0,0,0)

static __device__ __forceinline__ void gload_lds16(const void* g, void* l) {
  __builtin_amdgcn_global_load_lds((const __attribute__((address_space(1))) char*)g,
                                   (__attribute__((address_space(3))) char*)l, 16, 0, 0);
}

static __device__ __forceinline__ float fast_exp2(float x) {
  return __builtin_amdgcn_exp2f(x);
}
static __device__ __forceinline__ float fast_rcp(float x) {
  return __builtin_amdgcn_rcpf(x);
}

static __device__ __forceinline__ bf16x8 cvt8(f32x4 lo, f32x4 hi) {
  bf16x8 r;
  r[0]=(__bf16)lo[0]; r[1]=(__bf16)lo[1]; r[2]=(__bf16)lo[2]; r[3]=(__bf16)lo[3];
  r[4]=(__bf16)hi[0]; r[5]=(__bf16)hi[1]; r[6]=(__bf16)hi[2]; r[7]=(__bf16)hi[3];
  return r;
}

// ---------------- prep: W1->bf16, w2p pack, Vt build ----------------
// grid 298: [0,256) W1 cvt; [256,258) w2p; [258,294) pair-product cols; [294,298) static cols
__global__ __launch_bounds__(256) void prep_kernel(const float* __restrict__ W1,
                                                   const float* __restrict__ W2,
                                                   const float* __restrict__ gen,
                                                   __bf16* __restrict__ W1b,
                                                   __bf16* __restrict__ w2p,
                                                   __bf16* __restrict__ Vt) {
  const int bid = blockIdx.x, tid = threadIdx.x;
  __shared__ float Ga[NF*NF];
  __shared__ float Gb[NF*NF];
  if (bid < 256) {
    const int i = (bid*256 + tid)*4;
    float4 v = *(const float4*)(W1 + i);
    bf16x4 o; o[0]=(__bf16)v.x; o[1]=(__bf16)v.y; o[2]=(__bf16)v.z; o[3]=(__bf16)v.w;
    *(bf16x4*)(W1b + i) = o;
  } else if (bid < 258) {
    const int n = (bid-256)*256 + tid;
    bf16x8 o;
    #pragma unroll
    for (int r = 0; r < 8; ++r) o[r] = (__bf16)W2[r*DM + n];
    *(bf16x8*)(w2p + n*8) = o;
  } else if (bid < 294) {
    // pair p -> (r,s), r<=s: col 8+p = G_r G_s + (r!=s) G_s G_r
    const int p = bid - 258;
    int r = (p>=8)+(p>=15)+(p>=21)+(p>=26)+(p>=30)+(p>=33)+(p>=35);
    const int baser = r*8 - ((r*(r-1))>>1);
    const int s = r + p - baser;
    for (int i = tid; i < NF*NF; i += 256) {
      Ga[i] = gen[r*NF*NF + i];
      Gb[i] = gen[s*NF*NF + i];
    }
    __syncthreads();
    const int i  = tid >> 2;
    const int j0 = (tid & 3) * 16;
    float acc[16];
    #pragma unroll
    for (int jj = 0; jj < 16; ++jj) acc[jj] = 0.f;
    for (int k = 0; k < NF; ++k) {
      float a = Ga[i*NF + k];
      #pragma unroll
      for (int jj = 0; jj < 16; ++jj) acc[jj] += a * Gb[k*NF + j0 + jj];
    }
    if (r != s) {
      for (int k = 0; k < NF; ++k) {
        float a = Gb[i*NF + k];
        #pragma unroll
        for (int jj = 0; jj < 16; ++jj) acc[jj] += a * Ga[k*NF + j0 + jj];
      }
    }
    #pragma unroll
    for (int jj = 0; jj < 16; ++jj)
      Vt[(size_t)(i*NF + j0 + jj)*KU + 8 + p] = (__bf16)acc[jj];
  } else {
    // static cols: 0..7 = G_r[ij]; 44 = eye; 45..63 = 0
    const int q = bid - 294;
    #pragma unroll
    for (int v = 0; v < 4; ++v) {
      const int ij = q*1024 + tid*4 + v;
      bf16x8 g8;
      #pragma unroll
      for (int r = 0; r < 8; ++r) g8[r] = (__bf16)gen[r*NF*NF + ij];
      __bf16* row = Vt + (size_t)ij*KU;
      *(bf16x8*)row = g8;
      const float eye = ((ij >> 6) == (ij & 63)) ? 1.f : 0.f;
      bf16x4 e4; e4[0] = (__bf16)eye; e4[1] = (__bf16)0.f; e4[2] = (__bf16)0.f; e4[3] = (__bf16)0.f;
      *(bf16x4*)(row + 44) = e4;
      bf16x8 z8;
      #pragma unroll
      for (int k = 0; k < 8; ++k) z8[k] = (__bf16)0.f;
      *(bf16x8*)(row + 48) = z8;
      *(bf16x8*)(row + 56) = z8;
    }
  }
}

// ---------------- fused MLP + coefficients ----------------
// One WG per 32 batch rows. Computes Gs = xs@W1^T and Ge = xe@W1^T for its rows
// over the FULL n=512 (4 waves x 128-strip), keeps both in registers
// (acc[2 mats][2 mt][8 nt]), then does the 4-step gelu/W2/tanh reduction
// entirely on-chip and writes u[32][64].
// LDS: Bs = W1b K-chunk 512x64 bf16 (64 KB, gload_lds, XOR-swizzled src);
//      As = x chunk 2x32x64 bf16 (8 KB, reg-staged f32->bf16), aliased by
//      the epilogue's z-reduce buffers after the main loop.
__global__ __launch_bounds__(256, 2) void mlpc_kernel(
    const float* __restrict__ xs, const float* __restrict__ xe,
    const __bf16* __restrict__ W1b, const float* __restrict__ b1,
    const __bf16* __restrict__ w2p, const float* __restrict__ b2,
    const float* __restrict__ scale_p, __bf16* __restrict__ u) {
  __shared__ __bf16 Bs[512*64];   // 64 KB
  __shared__ char  AsRaw[8192];   // 8 KB: As (main loop) / zs+cshr (epilogue)
  __bf16* As = (__bf16*)AsRaw;

  const int tid = threadIdx.x;
  const int l = tid & 63, w = tid >> 6;
  const int lc = l & 15, lg = l >> 4;
  const int m0 = blockIdx.x * 32;

  // ---- A staging map: thread -> (mat, row, quarter of 64-float chunk)
  const int amat = tid >> 7;
  const int arow = (tid >> 2) & 31;
  const int aq   = tid & 3;
  const float* __restrict__ Xp = amat ? xe : xs;
  const float* asrc = Xp + (size_t)(m0 + arow)*DM + aq*16;
  const int ae = arow & 7;
  __bf16* adst0 = As + (amat*32 + arow)*64 + (((aq*2)    ) ^ ae)*8;
  __bf16* adst1 = As + (amat*32 + arow)*64 + (((aq*2) + 1) ^ ae)*8;

  // ---- B staging: 16 calls/K-step, dest linear tid*16, src slot pre-swizzled
  auto stageB = [&](int k0) {
    #pragma unroll
    for (int c = 0; c < 16; ++c) {
      const int row = c*32 + (tid >> 3);
      const int sp = (tid & 7) ^ (row & 7);
      gload_lds16(W1b + (size_t)row*DM + k0 + sp*8,
                  (char*)Bs + c*4096 + tid*16);
    }
  };

  f32x4 acc[2][2][8];
  #pragma unroll
  for (int mat = 0; mat < 2; ++mat)
    #pragma unroll
    for (int mt = 0; mt < 2; ++mt)
      #pragma unroll
      for (int nt = 0; nt < 8; ++nt) acc[mat][mt][nt] = (f32x4)0.f;

  // prologue: stage step 0
  f32x4 ar0 = *(const f32x4*)(asrc);
  f32x4 ar1 = *(const f32x4*)(asrc + 4);
  f32x4 ar2 = *(const f32x4*)(asrc + 8);
  f32x4 ar3 = *(const f32x4*)(asrc + 12);
  stageB(0);
  *(bf16x8*)adst0 = cvt8(ar0, ar1);
  *(bf16x8*)adst1 = cvt8(ar2, ar3);

  for (int ks = 0; ks < 8; ++ks) {
    __syncthreads();   // staging for ks visible (drains vmcnt + lds writes)
    if (ks < 7) {      // issue next A-loads; land during compute
      const float* p = asrc + (ks+1)*64;
      ar0 = *(const f32x4*)(p);
      ar1 = *(const f32x4*)(p + 4);
      ar2 = *(const f32x4*)(p + 8);
      ar3 = *(const f32x4*)(p + 12);
    }
    #pragma unroll
    for (int kk = 0; kk < 2; ++kk) {
      bf16x8 aF[2][2], bF[8];
      #pragma unroll
      for (int mat = 0; mat < 2; ++mat)
        #pragma unroll
        for (int mt = 0; mt < 2; ++mt) {
          const int row = mt*16 + lc;
          aF[mat][mt] = *(const bf16x8*)(As + (mat*32 + row)*64 + (((kk*4+lg) ^ (row & 7))*8));
        }
      #pragma unroll
      for (int nt = 0; nt < 8; ++nt) {
        const int row = w*128 + nt*16 + lc;
        bF[nt] = *(const bf16x8*)(Bs + row*64 + (((kk*4+lg) ^ (row & 7))*8));
      }
      #pragma unroll
      for (int mat = 0; mat < 2; ++mat)
        #pragma unroll
        for (int mt = 0; mt < 2; ++mt)
          #pragma unroll
          for (int nt = 0; nt < 8; ++nt)
            acc[mat][mt][nt] = MFMA16(aF[mat][mt], bF[nt], acc[mat][mt][nt]);
    }
    __syncthreads();   // all LDS reads for ks done
    if (ks < 7) {
      stageB((ks+1)*64);
      *(bf16x8*)adst0 = cvt8(ar0, ar1);
      *(bf16x8*)adst1 = cvt8(ar2, ar3);
    }
  }

  // ---- epilogue: coefficients fully on-chip ----
  // per-lane n-constants (n = w*128 + nt*16 + lc)
  float b1v[8]; bf16x8 w2b[8];
  #pragma unroll
  for (int nt = 0; nt < 8; ++nt) {
    const int n = w*128 + nt*16 + lc;
    b1v[nt] = b1[n];
    w2b[nt] = *(const bf16x8*)(w2p + (size_t)n*8);
  }
  // diff = Ge - Gs (raw); fold b1 into Gs
  #pragma unroll
  for (int mt = 0; mt < 2; ++mt)
    #pragma unroll
    for (int nt = 0; nt < 8; ++nt) {
      acc[1][mt][nt] = acc[1][mt][nt] - acc[0][mt][nt];
      #pragma unroll
      for (int rg = 0; rg < 4; ++rg) acc[0][mt][nt][rg] += b1v[nt];
    }
  const float scl = *scale_p;

  float* zs   = (float*)AsRaw;            // [4][32][8]
  float* cshr = (float*)(AsRaw + 4096);   // [32][8]
  const int pm = tid >> 3, pr = tid & 7;
  const float b2r = b2[pr];
  float csacc = 0.f;

  #pragma unroll
  for (int st = 0; st < 4; ++st) {
    const float tv = 0.125f + 0.25f*(float)st;
    float pz[2][4][8];
    #pragma unroll
    for (int mt = 0; mt < 2; ++mt)
      #pragma unroll
      for (int rg = 0; rg < 4; ++rg)
        #pragma unroll
        for (int r = 0; r < 8; ++r) pz[mt][rg][r] = 0.f;

    #pragma unroll
    for (int nt = 0; nt < 8; ++nt) {
      float w2x[8];
      #pragma unroll
      for (int r = 0; r < 8; ++r) w2x[r] = (float)w2b[nt][r];
      #pragma unroll
      for (int mt = 0; mt < 2; ++mt)
        #pragma unroll
        for (int rg = 0; rg < 4; ++rg) {
          const float mid = fmaf(tv, acc[1][mt][nt][rg], acc[0][mt][nt][rg]);
          const float g = mid * fast_rcp(1.f + fast_exp2(-2.4554669f * mid));
          #pragma unroll
          for (int r = 0; r < 8; ++r) pz[mt][rg][r] = fmaf(g, w2x[r], pz[mt][rg][r]);
        }
    }
    // reduce over the 16 lc lanes
    #pragma unroll
    for (int mt = 0; mt < 2; ++mt)
      #pragma unroll
      for (int rg = 0; rg < 4; ++rg)
        #pragma unroll
        for (int r = 0; r < 8; ++r) {
          float v = pz[mt][rg][r];
          v += __shfl_xor(v, 1); v += __shfl_xor(v, 2);
          v += __shfl_xor(v, 4); v += __shfl_xor(v, 8);
          pz[mt][rg][r] = v;
        }
    // lanes lc<8 write r=lc (static-unrolled select, no dynamic reg index)
    if (lc < 8) {
      #pragma unroll
      for (int mt = 0; mt < 2; ++mt)
        #pragma unroll
        for (int rg = 0; rg < 4; ++rg) {
          float v = pz[mt][rg][0];
          #pragma unroll
          for (int r = 1; r < 8; ++r) v = (lc == r) ? pz[mt][rg][r] : v;
          zs[w*256 + (mt*16 + lg*4 + rg)*8 + lc] = v;
        }
    }
    __syncthreads();
    {
      const float z = zs[pm*8 + pr] + zs[256 + pm*8 + pr]
                    + zs[512 + pm*8 + pr] + zs[768 + pm*8 + pr] + b2r;
      const float te = fast_exp2(2.8853901f * z);   // e^(2z); inf-safe
      csacc += 1.f - 2.f * fast_rcp(te + 1.f);
    }
    __syncthreads();   // zs reused next step
  }

  cshr[pm*8 + pr] = csacc * 0.25f * scl;   // * dt * scale
  __syncthreads();

  // u write: thread -> (row = tid>>3, seg = tid&7), cols seg*8..+8
  const int urow = tid >> 3, seg = tid & 7;
  bf16x8 o;
  #pragma unroll
  for (int j = 0; j < 8; ++j) {
    const int k = seg*8 + j;
    float val;
    if (k < 8) {
      val = cshr[urow*8 + k];
    } else if (k < 44) {
      const int p = k - 8;
      int r = (p>=8)+(p>=15)+(p>=21)+(p>=26)+(p>=30)+(p>=33)+(p>=35);
      const int baser = r*8 - ((r*(r-1))>>1);
      const int s2 = r + p - baser;
      val = 0.5f * cshr[urow*8 + r] * cshr[urow*8 + s2];
    } else if (k == 44) {
      val = 1.f;
    } else {
      val = 0.f;
    }
    o[j] = (__bf16)val;
  }
  *(bf16x8*)(u + (size_t)(m0 + urow)*KU + seg*8) = o;
}

// ---------------- K3: out[b][ij] = sum_k u[b][k] * Vt[ij][k]  (K=64) ----------------
// m-major grid; WG tile 64 rows x 256 cols, 4 waves side-by-side (each 64x64).
// B-rows permuted: frag b, lane lc <- col lc*4+b  => per-lane f32x4 stores.
__global__ __launch_bounds__(256) void out_gemm_kernel(
    const __bf16* __restrict__ u, const __bf16* __restrict__ Vt,
    float* __restrict__ out) {
  const int bid = blockIdx.x;
  const int mb = bid >> 4, nbq = bid & 15;
  const int tid = threadIdx.x;
  const int l = tid & 63, wv = tid >> 6;
  const int lc = l & 15, lg = l >> 4;
  const int m0 = mb*64;
  const int n0 = nbq*256 + wv*64;

  f32x4 acc[4][4];
  #pragma unroll
  for (int a = 0; a < 4; ++a)
    #pragma unroll
    for (int b = 0; b < 4; ++b) acc[a][b] = (f32x4)0.f;

  #pragma unroll
  for (int ks = 0; ks < 2; ++ks) {
    const int k0 = ks*32 + lg*8;
    bf16x8 aF[4], bF[4];
    #pragma unroll
    for (int a = 0; a < 4; ++a)
      aF[a] = *(const bf16x8*)(u + (size_t)(m0 + a*16 + lc)*KU + k0);
    #pragma unroll
    for (int b = 0; b < 4; ++b)
      bF[b] = *(const bf16x8*)(Vt + (size_t)(n0 + lc*4 + b)*KU + k0);
    #pragma unroll
    for (int a = 0; a < 4; ++a)
      #pragma unroll
      for (int b = 0; b < 4; ++b)
        acc[a][b] = MFMA16(aF[a], bF[b], acc[a][b]);
  }

  #pragma unroll
  for (int a = 0; a < 4; ++a)
    #pragma unroll
    for (int rg = 0; rg < 4; ++rg) {
      f32x4 o; o[0] = acc[a][0][rg]; o[1] = acc[a][1][rg];
      o[2] = acc[a][2][rg]; o[3] = acc[a][3][rg];
      *(f32x4*)(out + (size_t)(m0 + a*16 + lg*4 + rg)*4096 + n0 + lc*4) = o;
    }
}

extern "C" void kernel_launch(void* const* d_in, const int* in_sizes, int n_in,
                              void* d_out, int out_size, void* d_ws, size_t ws_size,
                              hipStream_t stream) {
  const float* xs    = (const float*)d_in[0];
  const float* xe    = (const float*)d_in[1];
  const float* W1    = (const float*)d_in[2];
  const float* b1    = (const float*)d_in[3];
  const float* W2    = (const float*)d_in[4];
  const float* b2    = (const float*)d_in[5];
  const float* gen   = (const float*)d_in[6];
  const float* scale = (const float*)d_in[7];

  char* ws = (char*)d_ws;
  __bf16* W1b = (__bf16*)ws;                                    // 512 KB
  __bf16* u   = (__bf16*)(ws + 512*1024);                       // 2 MB
  __bf16* Vt  = (__bf16*)(ws + 512*1024 + 2*1024*1024);         // 512 KB
  __bf16* w2p = (__bf16*)(ws + 512*1024 + 2*1024*1024 + 512*1024); // 8 KB

  prep_kernel<<<298, 256, 0, stream>>>(W1, W2, gen, W1b, w2p, Vt);
  mlpc_kernel<<<B_TOT/32, 256, 0, stream>>>(xs, xe, W1b, b1, w2p, b2, scale, u);
  out_gemm_kernel<<<256*16, 256, 0, stream>>>(u, Vt, (float*)d_out);
}

// Round 7
// 168.414 us; speedup vs baseline: 1.1141x; 1.1141x over previous
//
#include <hip/hip_runtime.h>

typedef __bf16 bf16x8 __attribute__((ext_vector_type(8)));
typedef __bf16 bf16x4 __attribute__((ext_vector_type(4)));
typedef float f32x4 __attribute__((ext_vector_type(4)));

#define B_TOT   16384
#define DM      512
#define NF      64
#define KU      64   // K for final GEMM: 8 G + 36 sym pairs + 1 eye + 19 zero

#define MFMA16(a,b,c) __builtin_amdgcn_mfma_f32_16x16x32_bf16(a,b,c,0,0,0)

static __device__ __forceinline__ void gload_lds16(const void* g, void* l) {
  __builtin_amdgcn_global_load_lds((const __attribute__((address_space(1))) char*)g,
                                   (__attribute__((address_space(3))) char*)l, 16, 0, 0);
}

static __device__ __forceinline__ float fast_exp2(float x) {
  return __builtin_amdgcn_exp2f(x);
}
static __device__ __forceinline__ float fast_rcp(float x) {
  return __builtin_amdgcn_rcpf(x);
}

static __device__ __forceinline__ bf16x8 cvt8(f32x4 lo, f32x4 hi) {
  bf16x8 r;
  r[0]=(__bf16)lo[0]; r[1]=(__bf16)lo[1]; r[2]=(__bf16)lo[2]; r[3]=(__bf16)lo[3];
  r[4]=(__bf16)hi[0]; r[5]=(__bf16)hi[1]; r[6]=(__bf16)hi[2]; r[7]=(__bf16)hi[3];
  return r;
}

// ---------------- prep: W1->bf16, w2p pack, Vt build ----------------
// grid 298: [0,256) W1 cvt; [256,258) w2p; [258,294) pair-product cols; [294,298) static cols
__global__ __launch_bounds__(256) void prep_kernel(const float* __restrict__ W1,
                                                   const float* __restrict__ W2,
                                                   const float* __restrict__ gen,
                                                   __bf16* __restrict__ W1b,
                                                   __bf16* __restrict__ w2p,
                                                   __bf16* __restrict__ Vt) {
  const int bid = blockIdx.x, tid = threadIdx.x;
  __shared__ float Ga[NF*NF];
  __shared__ float Gb[NF*NF];
  if (bid < 256) {
    const int i = (bid*256 + tid)*4;
    float4 v = *(const float4*)(W1 + i);
    bf16x4 o; o[0]=(__bf16)v.x; o[1]=(__bf16)v.y; o[2]=(__bf16)v.z; o[3]=(__bf16)v.w;
    *(bf16x4*)(W1b + i) = o;
  } else if (bid < 258) {
    const int n = (bid-256)*256 + tid;
    bf16x8 o;
    #pragma unroll
    for (int r = 0; r < 8; ++r) o[r] = (__bf16)W2[r*DM + n];
    *(bf16x8*)(w2p + n*8) = o;
  } else if (bid < 294) {
    // pair p -> (r,s), r<=s: col 8+p = G_r G_s + (r!=s) G_s G_r
    const int p = bid - 258;
    int r = (p>=8)+(p>=15)+(p>=21)+(p>=26)+(p>=30)+(p>=33)+(p>=35);
    const int baser = r*8 - ((r*(r-1))>>1);
    const int s = r + p - baser;
    for (int i = tid; i < NF*NF; i += 256) {
      Ga[i] = gen[r*NF*NF + i];
      Gb[i] = gen[s*NF*NF + i];
    }
    __syncthreads();
    const int i  = tid >> 2;
    const int j0 = (tid & 3) * 16;
    float acc[16];
    #pragma unroll
    for (int jj = 0; jj < 16; ++jj) acc[jj] = 0.f;
    for (int k = 0; k < NF; ++k) {
      float a = Ga[i*NF + k];
      #pragma unroll
      for (int jj = 0; jj < 16; ++jj) acc[jj] += a * Gb[k*NF + j0 + jj];
    }
    if (r != s) {
      for (int k = 0; k < NF; ++k) {
        float a = Gb[i*NF + k];
        #pragma unroll
        for (int jj = 0; jj < 16; ++jj) acc[jj] += a * Ga[k*NF + j0 + jj];
      }
    }
    #pragma unroll
    for (int jj = 0; jj < 16; ++jj)
      Vt[(size_t)(i*NF + j0 + jj)*KU + 8 + p] = (__bf16)acc[jj];
  } else {
    // static cols: 0..7 = G_r[ij]; 44 = eye; 45..63 = 0
    const int q = bid - 294;
    #pragma unroll
    for (int v = 0; v < 4; ++v) {
      const int ij = q*1024 + tid*4 + v;
      bf16x8 g8;
      #pragma unroll
      for (int r = 0; r < 8; ++r) g8[r] = (__bf16)gen[r*NF*NF + ij];
      __bf16* row = Vt + (size_t)ij*KU;
      *(bf16x8*)row = g8;
      const float eye = ((ij >> 6) == (ij & 63)) ? 1.f : 0.f;
      bf16x4 e4; e4[0] = (__bf16)eye; e4[1] = (__bf16)0.f; e4[2] = (__bf16)0.f; e4[3] = (__bf16)0.f;
      *(bf16x4*)(row + 44) = e4;
      bf16x8 z8;
      #pragma unroll
      for (int k = 0; k < 8; ++k) z8[k] = (__bf16)0.f;
      *(bf16x8*)(row + 48) = z8;
      *(bf16x8*)(row + 56) = z8;
    }
  }
}

// ---------------- K1a: Gs = xs@W1^T + b1, Ge = xe@W1^T + b1 ----------------
// Tile 128m x 64n, 4 waves stacked in m (each 32m x 64n), BK=64, 8 K-steps.
// A: f32 global -> regs (issued right after consume-barrier, hide under MFMA)
//    -> cvt bf16 -> swizzled ds_write_b128 after produce-barrier (T14 split).
// B: W1b bf16 via global_load_lds, src-swizzled.
// Swizzles: As slot' = s ^ (row&7);  Bs slot' = s ^ ((row>>2)&7).
// B-rows permuted: frag nt, lane lc <- row 4*lc+nt => per-lane 4 consecutive n => 8B stores.
// grid: bid = ntile*256 + mtile*2 + mat => XCD=bid%8 constant per (mtile,mat):
// all 8 ntiles sharing an A-stripe land on one XCD L2.
__global__ __launch_bounds__(256, 4) void mlp1_kernel(
    const float* __restrict__ xs, const float* __restrict__ xe,
    const __bf16* __restrict__ W1b, const float* __restrict__ b1,
    __bf16* __restrict__ Gsb, __bf16* __restrict__ Geb) {
  const int bid = blockIdx.x;
  const int mat = bid & 1;
  const int mtile = (bid >> 1) & 127;
  const int ntile = bid >> 8;
  const int m0 = mtile*128, n0 = ntile*64;
  const float* __restrict__ X = mat ? xe : xs;
  __bf16* __restrict__ G = mat ? Geb : Gsb;

  __shared__ __bf16 As[128*64];   // 16 KB; 8 slots/row, slot' = s ^ (row&7)
  __shared__ __bf16 Bs[64*64];    //  8 KB; 8 slots/row, slot' = s ^ ((row>>2)&7)

  const int tid = threadIdx.x;
  const int l = tid & 63, wm = tid >> 6;
  const int lc = l & 15, lg = l >> 4;

  // ---- staging maps
  const int arow = tid >> 3;      // 0..31 (c adds 32 each)
  const int aslt = tid & 7;
  const float* asrc = X + (size_t)(m0 + arow)*DM + aslt*8;
  const int brow = tid >> 3;
  const int bspw = (tid & 7) ^ ((brow >> 2) & 7);

  auto stageB = [&](int k0) {
    #pragma unroll
    for (int c = 0; c < 2; ++c) {
      gload_lds16(W1b + (size_t)(n0 + c*32 + brow)*DM + k0 + bspw*8,
                  (char*)Bs + c*4096 + tid*16);
    }
  };

  f32x4 ar[4][2];
  auto loadA = [&](int k0) {
    #pragma unroll
    for (int c = 0; c < 4; ++c) {
      const float* p = asrc + (size_t)c*32*DM + k0;
      ar[c][0] = *(const f32x4*)(p);
      ar[c][1] = *(const f32x4*)(p + 4);
    }
  };
  auto writeA = [&]() {
    #pragma unroll
    for (int c = 0; c < 4; ++c) {
      const int row = c*32 + arow;
      *(bf16x8*)(As + row*64 + ((aslt ^ (row & 7))*8)) = cvt8(ar[c][0], ar[c][1]);
    }
  };

  f32x4 acc[4][4];   // [mt][nt]
  #pragma unroll
  for (int a = 0; a < 4; ++a)
    #pragma unroll
    for (int b = 0; b < 4; ++b) acc[a][b] = (f32x4)0.f;

  // prologue
  loadA(0);
  stageB(0);
  writeA();

  for (int ks = 0; ks < 8; ++ks) {
    __syncthreads();   // staging(ks) visible (drains vmcnt + LDS writes)
    if (ks < 7) loadA((ks+1)*64);   // issue early: hides under MFMA (T14)
    #pragma unroll
    for (int kk = 0; kk < 2; ++kk) {
      bf16x8 aF[4], bF[4];
      #pragma unroll
      for (int mt = 0; mt < 4; ++mt) {
        const int row = wm*32 + ((mt&1)*16) + lc;       // rows wm*32 + mt*... 
        const int rr  = wm*32 + (mt>>1)*0;              // (placeholder, see below)
        (void)rr;
        aF[mt] = *(const bf16x8*)(As + ((wm*32 + (mt&1)*16 + lc) + (mt>>1)*64)*64
                                     + (((kk*4 + lg) ^ (((wm*32 + (mt&1)*16 + lc) + (mt>>1)*64) & 7))*8));
        (void)row;
      }
      #pragma unroll
      for (int nt = 0; nt < 4; ++nt) {
        const int row = lc*4 + nt;
        bF[nt] = *(const bf16x8*)(Bs + row*64 + (((kk*4 + lg) ^ ((row >> 2) & 7))*8));
      }
      #pragma unroll
      for (int mt = 0; mt < 4; ++mt)
        #pragma unroll
        for (int nt = 0; nt < 4; ++nt)
          acc[mt][nt] = MFMA16(aF[mt], bF[nt], acc[mt][nt]);
    }
    __syncthreads();   // all LDS reads for ks done
    if (ks < 7) {
      stageB((ks+1)*64);
      writeA();
    }
  }

  // epilogue: +b1, cvt bf16, packed 8B stores (per-lane n = 4*lc..4*lc+3)
  // m-rows: wave wm covers 32 rows at {wm*32, wm*32+16} + lg*4+rg, and the
  // +64 half via mt>>1 (aF mapping above): mt=0,1 -> rows wm*32+{0,16}; mt=2,3 -> +64.
  f32x4 b1v = *(const f32x4*)(b1 + n0 + lc*4);
  #pragma unroll
  for (int mt = 0; mt < 4; ++mt) {
    const int m = m0 + (mt>>1)*64 + wm*32 + (mt&1)*16 + lg*4;
    #pragma unroll
    for (int rg = 0; rg < 4; ++rg) {
      bf16x4 o;
      #pragma unroll
      for (int nt = 0; nt < 4; ++nt) o[nt] = (__bf16)(acc[mt][nt][rg] + b1v[nt]);
      *(bf16x4*)(G + (size_t)(m + rg)*DM + n0 + lc*4) = o;
    }
  }
}

// ---------------- K1b: coefficients ----------------
// per wave: 4 rows; lane = row_in_wave*16 + slice; slice covers n = {c*128 + slice*8 + i}
// coefficient fan-out goes through LDS (divergence-free reads; NO shfl in branches).
__global__ __launch_bounds__(256, 4) void coeff2_kernel(
    const __bf16* __restrict__ Gsb, const __bf16* __restrict__ Geb,
    const __bf16* __restrict__ w2p, const float* __restrict__ b2,
    const float* __restrict__ scale_p, __bf16* __restrict__ u) {
  const int tid = threadIdx.x;
  const int wv = tid >> 6, l = tid & 63;
  const int ls = l & 15;
  const int rib = wv*4 + (l >> 4);       // row in block, 0..15
  const int row = blockIdx.x*16 + rib;
  const size_t rb = (size_t)row * DM;

  __shared__ float cshr[16][8];

  float pz[4][8];
  #pragma unroll
  for (int st = 0; st < 4; ++st)
    #pragma unroll
    for (int r = 0; r < 8; ++r) pz[st][r] = 0.f;

  #pragma unroll
  for (int c = 0; c < 4; ++c) {
    const int nb = c*128 + ls*8;
    bf16x8 s8 = *(const bf16x8*)(Gsb + rb + nb);
    bf16x8 e8 = *(const bf16x8*)(Geb + rb + nb);
    #pragma unroll
    for (int i = 0; i < 8; ++i) {
      const float sv = (float)s8[i];
      const float dv = (float)e8[i] - sv;
      bf16x8 wv8 = *(const bf16x8*)(w2p + (size_t)(nb + i)*8);
      float w2f[8];
      #pragma unroll
      for (int r = 0; r < 8; ++r) w2f[r] = (float)wv8[r];
      #pragma unroll
      for (int st = 0; st < 4; ++st) {
        const float t = 0.125f + 0.25f*(float)st;
        const float mid = fmaf(t, dv, sv);
        // gelu ~= x * sigmoid(1.702 x); sigmoid via exp2 (hw v_exp_f32)
        const float g = mid * fast_rcp(1.f + fast_exp2(-2.4554669f * mid));
        #pragma unroll
        for (int r = 0; r < 8; ++r) pz[st][r] = fmaf(g, w2f[r], pz[st][r]);
      }
    }
  }

  // reduce over the 16 slices of this row
  #pragma unroll
  for (int st = 0; st < 4; ++st)
    #pragma unroll
    for (int r = 0; r < 8; ++r) {
      float v = pz[st][r];
      v += __shfl_xor(v, 1); v += __shfl_xor(v, 2);
      v += __shfl_xor(v, 4); v += __shfl_xor(v, 8);
      pz[st][r] = v;
    }

  // lane ls<8 finalizes r=ls for its row -> LDS
  const int rown = ls & 7;
  const float b2r = b2[rown];
  float sum = 0.f;
  #pragma unroll
  for (int st = 0; st < 4; ++st) {
    const float z = pz[st][rown] + b2r;
    const float te = fast_exp2(2.8853901f * z);   // e^(2z); inf-safe: tanh->1
    sum += 1.f - 2.f * fast_rcp(te + 1.f);
  }
  const float cs_own = sum * 0.25f * (*scale_p);  // * dt * scale
  if (ls < 8) cshr[rib][ls] = cs_own;
  __syncthreads();

  // write u[row][64]: slice ls writes cols 4ls..4ls+3 as one 8B store
  bf16x4 o;
  #pragma unroll
  for (int j = 0; j < 4; ++j) {
    const int k = ls*4 + j;
    float val;
    if (k < 8) {
      val = cshr[rib][k];
    } else if (k < 44) {
      const int p = k - 8;
      int r = (p>=8)+(p>=15)+(p>=21)+(p>=26)+(p>=30)+(p>=33)+(p>=35);
      const int baser = r*8 - ((r*(r-1))>>1);
      const int s2 = r + p - baser;
      val = 0.5f * cshr[rib][r] * cshr[rib][s2];
    } else if (k == 44) {
      val = 1.f;
    } else {
      val = 0.f;
    }
    o[j] = (__bf16)val;
  }
  *(bf16x4*)(u + (size_t)row*KU + ls*4) = o;
}

// ---------------- K3: out[b][ij] = sum_k u[b][k] * Vt[ij][k]  (K=64) ----------------
// m-major grid; WG tile 64 rows x 256 cols, 4 waves side-by-side (each 64x64).
// B-rows permuted: frag b, lane lc <- col lc*4+b  => per-lane f32x4 stores.
__global__ __launch_bounds__(256) void out_gemm_kernel(
    const __bf16* __restrict__ u, const __bf16* __restrict__ Vt,
    float* __restrict__ out) {
  const int bid = blockIdx.x;
  const int mb = bid >> 4, nbq = bid & 15;
  const int tid = threadIdx.x;
  const int l = tid & 63, wv = tid >> 6;
  const int lc = l & 15, lg = l >> 4;
  const int m0 = mb*64;
  const int n0 = nbq*256 + wv*64;

  f32x4 acc[4][4];
  #pragma unroll
  for (int a = 0; a < 4; ++a)
    #pragma unroll
    for (int b = 0; b < 4; ++b) acc[a][b] = (f32x4)0.f;

  #pragma unroll
  for (int ks = 0; ks < 2; ++ks) {
    const int k0 = ks*32 + lg*8;
    bf16x8 aF[4], bF[4];
    #pragma unroll
    for (int a = 0; a < 4; ++a)
      aF[a] = *(const bf16x8*)(u + (size_t)(m0 + a*16 + lc)*KU + k0);
    #pragma unroll
    for (int b = 0; b < 4; ++b)
      bF[b] = *(const bf16x8*)(Vt + (size_t)(n0 + lc*4 + b)*KU + k0);
    #pragma unroll
    for (int a = 0; a < 4; ++a)
      #pragma unroll
      for (int b = 0; b < 4; ++b)
        acc[a][b] = MFMA16(aF[a], bF[b], acc[a][b]);
  }

  #pragma unroll
  for (int a = 0; a < 4; ++a)
    #pragma unroll
    for (int rg = 0; rg < 4; ++rg) {
      f32x4 o; o[0] = acc[a][0][rg]; o[1] = acc[a][1][rg];
      o[2] = acc[a][2][rg]; o[3] = acc[a][3][rg];
      *(f32x4*)(out + (size_t)(m0 + a*16 + lg*4 + rg)*4096 + n0 + lc*4) = o;
    }
}

extern "C" void kernel_launch(void* const* d_in, const int* in_sizes, int n_in,
                              void* d_out, int out_size, void* d_ws, size_t ws_size,
                              hipStream_t stream) {
  const float* xs    = (const float*)d_in[0];
  const float* xe    = (const float*)d_in[1];
  const float* W1    = (const float*)d_in[2];
  const float* b1    = (const float*)d_in[3];
  const float* W2    = (const float*)d_in[4];
  const float* b2    = (const float*)d_in[5];
  const float* gen   = (const float*)d_in[6];
  const float* scale = (const float*)d_in[7];

  char* ws = (char*)d_ws;
  __bf16* W1b = (__bf16*)ws;                                    // 512 KB
  __bf16* u   = (__bf16*)(ws + 512*1024);                       // 2 MB
  __bf16* Vt  = (__bf16*)(ws + 512*1024 + 2*1024*1024);         // 512 KB
  __bf16* w2p = (__bf16*)(ws + 512*1024 + 2*1024*1024 + 512*1024); // 8 KB

  // Gs/Ge scratch lives in d_out (32 MB of 268), fully overwritten by K3.
  char* outc = (char*)d_out;
  __bf16* Gsb = (__bf16*)outc;
  __bf16* Geb = (__bf16*)(outc + (size_t)16*1024*1024);

  prep_kernel<<<298, 256, 0, stream>>>(W1, W2, gen, W1b, w2p, Vt);
  mlp1_kernel<<<2048, 256, 0, stream>>>(xs, xe, W1b, b1, Gsb, Geb);
  coeff2_kernel<<<B_TOT/16, 256, 0, stream>>>(Gsb, Geb, w2p, b2, scale, u);
  out_gemm_kernel<<<256*16, 256, 0, stream>>>(u, Vt, (float*)d_out);
}

// Round 8
// 147.997 us; speedup vs baseline: 1.2678x; 1.1380x over previous
//
#include <hip/hip_runtime.h>

typedef __bf16 bf16x8 __attribute__((ext_vector_type(8)));
typedef __bf16 bf16x4 __attribute__((ext_vector_type(4)));
typedef float f32x4 __attribute__((ext_vector_type(4)));

#define B_TOT   16384
#define DM      512
#define NF      64
#define KU      64   // K for final GEMM: 8 G + 36 sym pairs + 1 eye + 19 zero

#define MFMA16(a,b,c) __builtin_amdgcn_mfma_f32_16x16x32_bf16(a,b,c,0,0,0)

static __device__ __forceinline__ void gload_lds16(const void* g, void* l) {
  __builtin_amdgcn_global_load_lds((const __attribute__((address_space(1))) char*)g,
                                   (__attribute__((address_space(3))) char*)l, 16, 0, 0);
}

static __device__ __forceinline__ float fast_exp2(float x) {
  return __builtin_amdgcn_exp2f(x);
}
static __device__ __forceinline__ float fast_rcp(float x) {
  return __builtin_amdgcn_rcpf(x);
}

static __device__ __forceinline__ bf16x8 cvt8(f32x4 lo, f32x4 hi) {
  bf16x8 r;
  r[0]=(__bf16)lo[0]; r[1]=(__bf16)lo[1]; r[2]=(__bf16)lo[2]; r[3]=(__bf16)lo[3];
  r[4]=(__bf16)hi[0]; r[5]=(__bf16)hi[1]; r[6]=(__bf16)hi[2]; r[7]=(__bf16)hi[3];
  return r;
}

// ---------------- prep: W1->bf16, w2p pack, Vt build ----------------
// grid 298: [0,256) W1 cvt; [256,258) w2p; [258,294) pair-product cols; [294,298) static cols
__global__ __launch_bounds__(256) void prep_kernel(const float* __restrict__ W1,
                                                   const float* __restrict__ W2,
                                                   const float* __restrict__ gen,
                                                   __bf16* __restrict__ W1b,
                                                   __bf16* __restrict__ w2p,
                                                   __bf16* __restrict__ Vt) {
  const int bid = blockIdx.x, tid = threadIdx.x;
  __shared__ float Ga[NF*NF];
  __shared__ float Gb[NF*NF];
  if (bid < 256) {
    const int i = (bid*256 + tid)*4;
    float4 v = *(const float4*)(W1 + i);
    bf16x4 o; o[0]=(__bf16)v.x; o[1]=(__bf16)v.y; o[2]=(__bf16)v.z; o[3]=(__bf16)v.w;
    *(bf16x4*)(W1b + i) = o;
  } else if (bid < 258) {
    const int n = (bid-256)*256 + tid;
    bf16x8 o;
    #pragma unroll
    for (int r = 0; r < 8; ++r) o[r] = (__bf16)W2[r*DM + n];
    *(bf16x8*)(w2p + n*8) = o;
  } else if (bid < 294) {
    // pair p -> (r,s), r<=s: col 8+p = G_r G_s + (r!=s) G_s G_r
    const int p = bid - 258;
    int r = (p>=8)+(p>=15)+(p>=21)+(p>=26)+(p>=30)+(p>=33)+(p>=35);
    const int baser = r*8 - ((r*(r-1))>>1);
    const int s = r + p - baser;
    for (int i = tid; i < NF*NF; i += 256) {
      Ga[i] = gen[r*NF*NF + i];
      Gb[i] = gen[s*NF*NF + i];
    }
    __syncthreads();
    const int i  = tid >> 2;
    const int j0 = (tid & 3) * 16;
    float acc[16];
    #pragma unroll
    for (int jj = 0; jj < 16; ++jj) acc[jj] = 0.f;
    for (int k = 0; k < NF; ++k) {
      float a = Ga[i*NF + k];
      #pragma unroll
      for (int jj = 0; jj < 16; ++jj) acc[jj] += a * Gb[k*NF + j0 + jj];
    }
    if (r != s) {
      for (int k = 0; k < NF; ++k) {
        float a = Gb[i*NF + k];
        #pragma unroll
        for (int jj = 0; jj < 16; ++jj) acc[jj] += a * Ga[k*NF + j0 + jj];
      }
    }
    #pragma unroll
    for (int jj = 0; jj < 16; ++jj)
      Vt[(size_t)(i*NF + j0 + jj)*KU + 8 + p] = (__bf16)acc[jj];
  } else {
    // static cols: 0..7 = G_r[ij]; 44 = eye; 45..63 = 0
    const int q = bid - 294;
    #pragma unroll
    for (int v = 0; v < 4; ++v) {
      const int ij = q*1024 + tid*4 + v;
      bf16x8 g8;
      #pragma unroll
      for (int r = 0; r < 8; ++r) g8[r] = (__bf16)gen[r*NF*NF + ij];
      __bf16* row = Vt + (size_t)ij*KU;
      *(bf16x8*)row = g8;
      const float eye = ((ij >> 6) == (ij & 63)) ? 1.f : 0.f;
      bf16x4 e4; e4[0] = (__bf16)eye; e4[1] = (__bf16)0.f; e4[2] = (__bf16)0.f; e4[3] = (__bf16)0.f;
      *(bf16x4*)(row + 44) = e4;
      bf16x8 z8;
      #pragma unroll
      for (int k = 0; k < 8; ++k) z8[k] = (__bf16)0.f;
      *(bf16x8*)(row + 48) = z8;
      *(bf16x8*)(row + 56) = z8;
    }
  }
}

// ---------------- K1a: Gs = xs@W1^T + b1, Ge = xe@W1^T + b1 ----------------
// EXACTLY R4's verified mlp1 (tile 128x128, 4 waves 2x2, BK=64, 8 K-steps,
// As/Bs 16 KB each, A-swizzle e=row&7, B-swizzle e=(row>>2)&7, B-rows permuted
// frag nt, lane lc <- row 4*lc+nt) with ONE change: A is staged from f32
// global via regs + cvt + swizzled ds_write_b128 (same final As layout as
// R4's gload_lds of pre-converted data), removing the separate X-cvt pass.
// A-loads issue right after the consume-barrier (hide under MFMA); writes
// after the produce-barrier (T14 split).
__global__ __launch_bounds__(256, 3) void mlp1_kernel(
    const float* __restrict__ xs, const float* __restrict__ xe,
    const __bf16* __restrict__ W1b, const float* __restrict__ b1,
    __bf16* __restrict__ Gsb, __bf16* __restrict__ Geb) {
  const int bid = blockIdx.x;
  const int mtile = bid & 127;
  const int nm = bid >> 7;
  const int mat = nm & 1;
  const int ntile = nm >> 1;
  const int m0 = mtile*128, n0 = ntile*128;
  const float* __restrict__ X = mat ? xe : xs;
  __bf16* __restrict__ G = mat ? Geb : Gsb;

  __shared__ __bf16 As[128*64];   // 16 KB; 8 slots/row, content chunk s at slot s^(row&7)
  __shared__ __bf16 Bs[128*64];   // 16 KB; 8 slots/row, content chunk s at slot s^((row>>2)&7)

  const int tid = threadIdx.x;
  const int l = tid & 63, w = tid >> 6;
  const int lc = l & 15, lg = l >> 4;
  const int wm = w >> 1, wn = w & 1;

  // ---- A staging map: thread -> row = tid>>3 (+c*32), k-chunk q = tid&7
  const int arow = tid >> 3;      // 0..31
  const int aq   = tid & 7;
  const float* asrc = X + (size_t)(m0 + arow)*DM + aq*8;

  auto stageB = [&](int k0) {
    #pragma unroll
    for (int c = 0; c < 4; ++c) {
      const int row = c*32 + (tid >> 3);
      const int spB = (tid & 7) ^ ((row >> 2) & 7);
      gload_lds16(W1b + (size_t)(n0 + row)*DM + k0 + spB*8,
                  (char*)Bs + c*4096 + tid*16);
    }
  };

  f32x4 ar[4][2];
  auto loadA = [&](int k0) {
    #pragma unroll
    for (int c = 0; c < 4; ++c) {
      const float* p = asrc + (size_t)c*32*DM + k0;
      ar[c][0] = *(const f32x4*)(p);
      ar[c][1] = *(const f32x4*)(p + 4);
    }
  };
  auto writeA = [&]() {
    #pragma unroll
    for (int c = 0; c < 4; ++c) {
      const int row = c*32 + arow;
      *(bf16x8*)(As + row*64 + ((aq ^ (row & 7))*8)) = cvt8(ar[c][0], ar[c][1]);
    }
  };

  f32x4 acc[4][4];
  #pragma unroll
  for (int a = 0; a < 4; ++a)
    #pragma unroll
    for (int b = 0; b < 4; ++b) acc[a][b] = (f32x4)0.f;

  // prologue: stage K-step 0
  loadA(0);
  stageB(0);
  writeA();

  for (int ks = 0; ks < 8; ++ks) {
    __syncthreads();   // staging(ks) visible (drains vmcnt + LDS writes)
    if (ks < 7) loadA((ks+1)*64);   // issue early: hides under MFMA
    #pragma unroll
    for (int kk = 0; kk < 2; ++kk) {
      bf16x8 aF[4], bF[4];
      #pragma unroll
      for (int mt = 0; mt < 4; ++mt) {
        const int row = wm*64 + mt*16 + lc;
        const int sp = (kk*4 + lg) ^ (row & 7);
        aF[mt] = *(const bf16x8*)(As + row*64 + sp*8);
      }
      #pragma unroll
      for (int nt = 0; nt < 4; ++nt) {
        const int row = wn*64 + lc*4 + nt;
        const int sp = (kk*4 + lg) ^ ((row >> 2) & 7);
        bF[nt] = *(const bf16x8*)(Bs + row*64 + sp*8);
      }
      #pragma unroll
      for (int mt = 0; mt < 4; ++mt)
        #pragma unroll
        for (int nt = 0; nt < 4; ++nt)
          acc[mt][nt] = MFMA16(aF[mt], bF[nt], acc[mt][nt]);
    }
    __syncthreads();   // all LDS reads for ks done before overwrite
    if (ks < 7) {
      stageB((ks+1)*64);
      writeA();
    }
  }

  // epilogue: +b1, cvt bf16, packed 8B stores (per-lane n = 4*lc..4*lc+3)
  f32x4 b1v = *(const f32x4*)(b1 + n0 + wn*64 + lc*4);
  #pragma unroll
  for (int mt = 0; mt < 4; ++mt) {
    const int m = m0 + wm*64 + mt*16 + lg*4;
    #pragma unroll
    for (int rg = 0; rg < 4; ++rg) {
      bf16x4 o;
      #pragma unroll
      for (int nt = 0; nt < 4; ++nt) o[nt] = (__bf16)(acc[mt][nt][rg] + b1v[nt]);
      *(bf16x4*)(G + (size_t)(m + rg)*DM + n0 + wn*64 + lc*4) = o;
    }
  }
}

// ---------------- K1b: coefficients ----------------
// per wave: 4 rows; lane = row_in_wave*16 + slice; slice covers n = {c*128 + slice*8 + i}
// coefficient fan-out goes through LDS (divergence-free reads; NO shfl in branches).
__global__ __launch_bounds__(256, 4) void coeff2_kernel(
    const __bf16* __restrict__ Gsb, const __bf16* __restrict__ Geb,
    const __bf16* __restrict__ w2p, const float* __restrict__ b2,
    const float* __restrict__ scale_p, __bf16* __restrict__ u) {
  const int tid = threadIdx.x;
  const int wv = tid >> 6, l = tid & 63;
  const int ls = l & 15;
  const int rib = wv*4 + (l >> 4);       // row in block, 0..15
  const int row = blockIdx.x*16 + rib;
  const size_t rb = (size_t)row * DM;

  __shared__ float cshr[16][8];

  float pz[4][8];
  #pragma unroll
  for (int st = 0; st < 4; ++st)
    #pragma unroll
    for (int r = 0; r < 8; ++r) pz[st][r] = 0.f;

  #pragma unroll
  for (int c = 0; c < 4; ++c) {
    const int nb = c*128 + ls*8;
    bf16x8 s8 = *(const bf16x8*)(Gsb + rb + nb);
    bf16x8 e8 = *(const bf16x8*)(Geb + rb + nb);
    #pragma unroll
    for (int i = 0; i < 8; ++i) {
      const float sv = (float)s8[i];
      const float dv = (float)e8[i] - sv;
      bf16x8 wv8 = *(const bf16x8*)(w2p + (size_t)(nb + i)*8);
      float w2f[8];
      #pragma unroll
      for (int r = 0; r < 8; ++r) w2f[r] = (float)wv8[r];
      #pragma unroll
      for (int st = 0; st < 4; ++st) {
        const float t = 0.125f + 0.25f*(float)st;
        const float mid = fmaf(t, dv, sv);
        // gelu ~= x * sigmoid(1.702 x); sigmoid via exp2 (hw v_exp_f32)
        const float g = mid * fast_rcp(1.f + fast_exp2(-2.4554669f * mid));
        #pragma unroll
        for (int r = 0; r < 8; ++r) pz[st][r] = fmaf(g, w2f[r], pz[st][r]);
      }
    }
  }

  // reduce over the 16 slices of this row
  #pragma unroll
  for (int st = 0; st < 4; ++st)
    #pragma unroll
    for (int r = 0; r < 8; ++r) {
      float v = pz[st][r];
      v += __shfl_xor(v, 1); v += __shfl_xor(v, 2);
      v += __shfl_xor(v, 4); v += __shfl_xor(v, 8);
      pz[st][r] = v;
    }

  // lane ls<8 finalizes r=ls for its row -> LDS
  const int rown = ls & 7;
  const float b2r = b2[rown];
  float sum = 0.f;
  #pragma unroll
  for (int st = 0; st < 4; ++st) {
    const float z = pz[st][rown] + b2r;
    const float te = fast_exp2(2.8853901f * z);   // e^(2z); inf-safe: tanh->1
    sum += 1.f - 2.f * fast_rcp(te + 1.f);
  }
  const float cs_own = sum * 0.25f * (*scale_p);  // * dt * scale
  if (ls < 8) cshr[rib][ls] = cs_own;
  __syncthreads();

  // write u[row][64]: slice ls writes cols 4ls..4ls+3 as one 8B store
  bf16x4 o;
  #pragma unroll
  for (int j = 0; j < 4; ++j) {
    const int k = ls*4 + j;
    float val;
    if (k < 8) {
      val = cshr[rib][k];
    } else if (k < 44) {
      const int p = k - 8;
      int r = (p>=8)+(p>=15)+(p>=21)+(p>=26)+(p>=30)+(p>=33)+(p>=35);
      const int baser = r*8 - ((r*(r-1))>>1);
      const int s2 = r + p - baser;
      val = 0.5f * cshr[rib][r] * cshr[rib][s2];
    } else if (k == 44) {
      val = 1.f;
    } else {
      val = 0.f;
    }
    o[j] = (__bf16)val;
  }
  *(bf16x4*)(u + (size_t)row*KU + ls*4) = o;
}

// ---------------- K3: out[b][ij] = sum_k u[b][k] * Vt[ij][k]  (K=64) ----------------
// m-major grid; WG tile 64 rows x 256 cols, 4 waves side-by-side (each 64x64).
// B-rows permuted: frag b, lane lc <- col lc*4+b  => per-lane f32x4 stores.
__global__ __launch_bounds__(256) void out_gemm_kernel(
    const __bf16* __restrict__ u, const __bf16* __restrict__ Vt,
    float* __restrict__ out) {
  const int bid = blockIdx.x;
  const int mb = bid >> 4, nbq = bid & 15;
  const int tid = threadIdx.x;
  const int l = tid & 63, wv = tid >> 6;
  const int lc = l & 15, lg = l >> 4;
  const int m0 = mb*64;
  const int n0 = nbq*256 + wv*64;

  f32x4 acc[4][4];
  #pragma unroll
  for (int a = 0; a < 4; ++a)
    #pragma unroll
    for (int b = 0; b < 4; ++b) acc[a][b] = (f32x4)0.f;

  #pragma unroll
  for (int ks = 0; ks < 2; ++ks) {
    const int k0 = ks*32 + lg*8;
    bf16x8 aF[4], bF[4];
    #pragma unroll
    for (int a = 0; a < 4; ++a)
      aF[a] = *(const bf16x8*)(u + (size_t)(m0 + a*16 + lc)*KU + k0);
    #pragma unroll
    for (int b = 0; b < 4; ++b)
      bF[b] = *(const bf16x8*)(Vt + (size_t)(n0 + lc*4 + b)*KU + k0);
    #pragma unroll
    for (int a = 0; a < 4; ++a)
      #pragma unroll
      for (int b = 0; b < 4; ++b)
        acc[a][b] = MFMA16(aF[a], bF[b], acc[a][b]);
  }

  #pragma unroll
  for (int a = 0; a < 4; ++a)
    #pragma unroll
    for (int rg = 0; rg < 4; ++rg) {
      f32x4 o; o[0] = acc[a][0][rg]; o[1] = acc[a][1][rg];
      o[2] = acc[a][2][rg]; o[3] = acc[a][3][rg];
      *(f32x4*)(out + (size_t)(m0 + a*16 + lg*4 + rg)*4096 + n0 + lc*4) = o;
    }
}

extern "C" void kernel_launch(void* const* d_in, const int* in_sizes, int n_in,
                              void* d_out, int out_size, void* d_ws, size_t ws_size,
                              hipStream_t stream) {
  const float* xs    = (const float*)d_in[0];
  const float* xe    = (const float*)d_in[1];
  const float* W1    = (const float*)d_in[2];
  const float* b1    = (const float*)d_in[3];
  const float* W2    = (const float*)d_in[4];
  const float* b2    = (const float*)d_in[5];
  const float* gen   = (const float*)d_in[6];
  const float* scale = (const float*)d_in[7];

  char* ws = (char*)d_ws;
  __bf16* W1b = (__bf16*)ws;                                    // 512 KB
  __bf16* u   = (__bf16*)(ws + 512*1024);                       // 2 MB
  __bf16* Vt  = (__bf16*)(ws + 512*1024 + 2*1024*1024);         // 512 KB
  __bf16* w2p = (__bf16*)(ws + 512*1024 + 2*1024*1024 + 512*1024); // 8 KB

  // Gs/Ge scratch lives in d_out (32 MB of 268), fully overwritten by K3.
  char* outc = (char*)d_out;
  __bf16* Gsb = (__bf16*)outc;
  __bf16* Geb = (__bf16*)(outc + (size_t)16*1024*1024);

  prep_kernel<<<298, 256, 0, stream>>>(W1, W2, gen, W1b, w2p, Vt);
  mlp1_kernel<<<1024, 256, 0, stream>>>(xs, xe, W1b, b1, Gsb, Geb);
  coeff2_kernel<<<B_TOT/16, 256, 0, stream>>>(Gsb, Geb, w2p, b2, scale, u);
  out_gemm_kernel<<<256*16, 256, 0, stream>>>(u, Vt, (float*)d_out);
}

// Round 9
// 141.751 us; speedup vs baseline: 1.3236x; 1.0441x over previous
//
#include <hip/hip_runtime.h>

typedef __bf16 bf16x8 __attribute__((ext_vector_type(8)));
typedef __bf16 bf16x4 __attribute__((ext_vector_type(4)));
typedef float f32x4 __attribute__((ext_vector_type(4)));

#define B_TOT   16384
#define DM      512
#define NF      64
#define KU      64   // K for final GEMM: 8 G + 36 sym pairs + 1 eye + 19 zero

#define MFMA16(a,b,c) __builtin_amdgcn_mfma_f32_16x16x32_bf16(a,b,c,0,0,0)

static __device__ __forceinline__ void gload_lds16(const void* g, void* l) {
  __builtin_amdgcn_global_load_lds((const __attribute__((address_space(1))) char*)g,
                                   (__attribute__((address_space(3))) char*)l, 16, 0, 0);
}

static __device__ __forceinline__ float fast_exp2(float x) {
  return __builtin_amdgcn_exp2f(x);
}
static __device__ __forceinline__ float fast_rcp(float x) {
  return __builtin_amdgcn_rcpf(x);
}

static __device__ __forceinline__ bf16x8 cvt8(f32x4 lo, f32x4 hi) {
  bf16x8 r;
  r[0]=(__bf16)lo[0]; r[1]=(__bf16)lo[1]; r[2]=(__bf16)lo[2]; r[3]=(__bf16)lo[3];
  r[4]=(__bf16)hi[0]; r[5]=(__bf16)hi[1]; r[6]=(__bf16)hi[2]; r[7]=(__bf16)hi[3];
  return r;
}

// ---------------- prep: W1->bf16, w2p pack, Vt build ----------------
// grid 298: [0,256) W1 cvt; [256,258) w2p; [258,294) pair-product cols; [294,298) static cols
__global__ __launch_bounds__(256) void prep_kernel(const float* __restrict__ W1,
                                                   const float* __restrict__ W2,
                                                   const float* __restrict__ gen,
                                                   __bf16* __restrict__ W1b,
                                                   __bf16* __restrict__ w2p,
                                                   __bf16* __restrict__ Vt) {
  const int bid = blockIdx.x, tid = threadIdx.x;
  __shared__ float Ga[NF*NF];
  __shared__ float Gb[NF*NF];
  if (bid < 256) {
    const int i = (bid*256 + tid)*4;
    float4 v = *(const float4*)(W1 + i);
    bf16x4 o; o[0]=(__bf16)v.x; o[1]=(__bf16)v.y; o[2]=(__bf16)v.z; o[3]=(__bf16)v.w;
    *(bf16x4*)(W1b + i) = o;
  } else if (bid < 258) {
    const int n = (bid-256)*256 + tid;
    bf16x8 o;
    #pragma unroll
    for (int r = 0; r < 8; ++r) o[r] = (__bf16)W2[r*DM + n];
    *(bf16x8*)(w2p + n*8) = o;
  } else if (bid < 294) {
    // pair p -> (r,s), r<=s: col 8+p = G_r G_s + (r!=s) G_s G_r
    const int p = bid - 258;
    int r = (p>=8)+(p>=15)+(p>=21)+(p>=26)+(p>=30)+(p>=33)+(p>=35);
    const int baser = r*8 - ((r*(r-1))>>1);
    const int s = r + p - baser;
    for (int i = tid; i < NF*NF; i += 256) {
      Ga[i] = gen[r*NF*NF + i];
      Gb[i] = gen[s*NF*NF + i];
    }
    __syncthreads();
    const int i  = tid >> 2;
    const int j0 = (tid & 3) * 16;
    float acc[16];
    #pragma unroll
    for (int jj = 0; jj < 16; ++jj) acc[jj] = 0.f;
    for (int k = 0; k < NF; ++k) {
      float a = Ga[i*NF + k];
      #pragma unroll
      for (int jj = 0; jj < 16; ++jj) acc[jj] += a * Gb[k*NF + j0 + jj];
    }
    if (r != s) {
      for (int k = 0; k < NF; ++k) {
        float a = Gb[i*NF + k];
        #pragma unroll
        for (int jj = 0; jj < 16; ++jj) acc[jj] += a * Ga[k*NF + j0 + jj];
      }
    }
    #pragma unroll
    for (int jj = 0; jj < 16; ++jj)
      Vt[(size_t)(i*NF + j0 + jj)*KU + 8 + p] = (__bf16)acc[jj];
  } else {
    // static cols: 0..7 = G_r[ij]; 44 = eye; 45..63 = 0
    const int q = bid - 294;
    #pragma unroll
    for (int v = 0; v < 4; ++v) {
      const int ij = q*1024 + tid*4 + v;
      bf16x8 g8;
      #pragma unroll
      for (int r = 0; r < 8; ++r) g8[r] = (__bf16)gen[r*NF*NF + ij];
      __bf16* row = Vt + (size_t)ij*KU;
      *(bf16x8*)row = g8;
      const float eye = ((ij >> 6) == (ij & 63)) ? 1.f : 0.f;
      bf16x4 e4; e4[0] = (__bf16)eye; e4[1] = (__bf16)0.f; e4[2] = (__bf16)0.f; e4[3] = (__bf16)0.f;
      *(bf16x4*)(row + 44) = e4;
      bf16x8 z8;
      #pragma unroll
      for (int k = 0; k < 8; ++k) z8[k] = (__bf16)0.f;
      *(bf16x8*)(row + 48) = z8;
      *(bf16x8*)(row + 56) = z8;
    }
  }
}

// ---------------- K1a: Gs = xs@W1^T + b1, Ge = xe@W1^T + b1 ----------------
// R8's verified tile/layout (128x128, 4 waves 2x2, BK=64, 8 K-steps, A-swizzle
// e=row&7, B-swizzle e=(row>>2)&7, B-rows permuted frag nt <- row 4*lc+nt),
// now DOUBLE-BUFFERED with ONE barrier per K-step: loads for ks+1 (A f32->reg
// and B gload_lds) issue right after barrier #ks and are drained at barrier
// #ks+1 — a full compute phase (~350 cyc) later — instead of immediately.
// Hazards: stage targets buf^1 whose last readers finished before barrier #ks;
// writeA(ks+1) runs after compute(ks); __syncthreads drains vmcnt+lgkm.
__global__ __launch_bounds__(256, 2) void mlp1_kernel(
    const float* __restrict__ xs, const float* __restrict__ xe,
    const __bf16* __restrict__ W1b, const float* __restrict__ b1,
    __bf16* __restrict__ Gsb, __bf16* __restrict__ Geb) {
  const int bid = blockIdx.x;
  const int mtile = bid & 127;
  const int nm = bid >> 7;
  const int mat = nm & 1;
  const int ntile = nm >> 1;
  const int m0 = mtile*128, n0 = ntile*128;
  const float* __restrict__ X = mat ? xe : xs;
  __bf16* __restrict__ G = mat ? Geb : Gsb;

  __shared__ __bf16 As[2][128*64];   // 2 x 16 KB; chunk s at slot s^(row&7)
  __shared__ __bf16 Bs[2][128*64];   // 2 x 16 KB; chunk s at slot s^((row>>2)&7)

  const int tid = threadIdx.x;
  const int l = tid & 63, w = tid >> 6;
  const int lc = l & 15, lg = l >> 4;
  const int wm = w >> 1, wn = w & 1;

  // ---- A staging map: thread -> row = tid>>3 (+c*32), k-chunk q = tid&7
  const int arow = tid >> 3;      // 0..31
  const int aq   = tid & 7;
  const float* asrc = X + (size_t)(m0 + arow)*DM + aq*8;

  auto stageB = [&](int k0, int buf) {
    #pragma unroll
    for (int c = 0; c < 4; ++c) {
      const int row = c*32 + (tid >> 3);
      const int spB = (tid & 7) ^ ((row >> 2) & 7);
      gload_lds16(W1b + (size_t)(n0 + row)*DM + k0 + spB*8,
                  (char*)(&Bs[buf][0]) + c*4096 + tid*16);
    }
  };

  f32x4 ar[4][2];
  auto loadA = [&](int k0) {
    #pragma unroll
    for (int c = 0; c < 4; ++c) {
      const float* p = asrc + (size_t)c*32*DM + k0;
      ar[c][0] = *(const f32x4*)(p);
      ar[c][1] = *(const f32x4*)(p + 4);
    }
  };
  auto writeA = [&](int buf) {
    #pragma unroll
    for (int c = 0; c < 4; ++c) {
      const int row = c*32 + arow;
      *(bf16x8*)(&As[buf][0] + row*64 + ((aq ^ (row & 7))*8)) = cvt8(ar[c][0], ar[c][1]);
    }
  };

  f32x4 acc[4][4];
  #pragma unroll
  for (int a = 0; a < 4; ++a)
    #pragma unroll
    for (int b = 0; b < 4; ++b) acc[a][b] = (f32x4)0.f;

  // prologue: fully stage K-step 0 into buf 0
  loadA(0);
  stageB(0, 0);
  writeA(0);

  for (int ks = 0; ks < 8; ++ks) {
    const int cb = ks & 1, nb = cb ^ 1;
    __syncthreads();   // staging(ks) complete & visible (vmcnt+lgkm drained)
    if (ks < 7) {
      loadA((ks+1)*64);       // issue early: drained only at barrier #ks+1
      stageB((ks+1)*64, nb);  // gload_lds into the other buffer
    }
    #pragma unroll
    for (int kk = 0; kk < 2; ++kk) {
      bf16x8 aF[4], bF[4];
      #pragma unroll
      for (int mt = 0; mt < 4; ++mt) {
        const int row = wm*64 + mt*16 + lc;
        const int sp = (kk*4 + lg) ^ (row & 7);
        aF[mt] = *(const bf16x8*)(&As[cb][0] + row*64 + sp*8);
      }
      #pragma unroll
      for (int nt = 0; nt < 4; ++nt) {
        const int row = wn*64 + lc*4 + nt;
        const int sp = (kk*4 + lg) ^ ((row >> 2) & 7);
        bF[nt] = *(const bf16x8*)(&Bs[cb][0] + row*64 + sp*8);
      }
      #pragma unroll
      for (int mt = 0; mt < 4; ++mt)
        #pragma unroll
        for (int nt = 0; nt < 4; ++nt)
          acc[mt][nt] = MFMA16(aF[mt], bF[nt], acc[mt][nt]);
    }
    if (ks < 7) writeA(nb);   // A regs -> other buffer, after compute
  }

  // epilogue: +b1, cvt bf16, packed 8B stores (per-lane n = 4*lc..4*lc+3)
  f32x4 b1v = *(const f32x4*)(b1 + n0 + wn*64 + lc*4);
  #pragma unroll
  for (int mt = 0; mt < 4; ++mt) {
    const int m = m0 + wm*64 + mt*16 + lg*4;
    #pragma unroll
    for (int rg = 0; rg < 4; ++rg) {
      bf16x4 o;
      #pragma unroll
      for (int nt = 0; nt < 4; ++nt) o[nt] = (__bf16)(acc[mt][nt][rg] + b1v[nt]);
      *(bf16x4*)(G + (size_t)(m + rg)*DM + n0 + wn*64 + lc*4) = o;
    }
  }
}

// ---------------- K1b: coefficients ----------------
// per wave: 4 rows; lane = row_in_wave*16 + slice; slice covers n = {c*128 + slice*8 + i}
// coefficient fan-out goes through LDS (divergence-free reads; NO shfl in branches).
__global__ __launch_bounds__(256, 4) void coeff2_kernel(
    const __bf16* __restrict__ Gsb, const __bf16* __restrict__ Geb,
    const __bf16* __restrict__ w2p, const float* __restrict__ b2,
    const float* __restrict__ scale_p, __bf16* __restrict__ u) {
  const int tid = threadIdx.x;
  const int wv = tid >> 6, l = tid & 63;
  const int ls = l & 15;
  const int rib = wv*4 + (l >> 4);       // row in block, 0..15
  const int row = blockIdx.x*16 + rib;
  const size_t rb = (size_t)row * DM;

  __shared__ float cshr[16][8];

  float pz[4][8];
  #pragma unroll
  for (int st = 0; st < 4; ++st)
    #pragma unroll
    for (int r = 0; r < 8; ++r) pz[st][r] = 0.f;

  #pragma unroll
  for (int c = 0; c < 4; ++c) {
    const int nb = c*128 + ls*8;
    bf16x8 s8 = *(const bf16x8*)(Gsb + rb + nb);
    bf16x8 e8 = *(const bf16x8*)(Geb + rb + nb);
    #pragma unroll
    for (int i = 0; i < 8; ++i) {
      const float sv = (float)s8[i];
      const float dv = (float)e8[i] - sv;
      bf16x8 wv8 = *(const bf16x8*)(w2p + (size_t)(nb + i)*8);
      float w2f[8];
      #pragma unroll
      for (int r = 0; r < 8; ++r) w2f[r] = (float)wv8[r];
      #pragma unroll
      for (int st = 0; st < 4; ++st) {
        const float t = 0.125f + 0.25f*(float)st;
        const float mid = fmaf(t, dv, sv);
        // gelu ~= x * sigmoid(1.702 x); sigmoid via exp2 (hw v_exp_f32)
        const float g = mid * fast_rcp(1.f + fast_exp2(-2.4554669f * mid));
        #pragma unroll
        for (int r = 0; r < 8; ++r) pz[st][r] = fmaf(g, w2f[r], pz[st][r]);
      }
    }
  }

  // reduce over the 16 slices of this row
  #pragma unroll
  for (int st = 0; st < 4; ++st)
    #pragma unroll
    for (int r = 0; r < 8; ++r) {
      float v = pz[st][r];
      v += __shfl_xor(v, 1); v += __shfl_xor(v, 2);
      v += __shfl_xor(v, 4); v += __shfl_xor(v, 8);
      pz[st][r] = v;
    }

  // lane ls<8 finalizes r=ls for its row -> LDS
  const int rown = ls & 7;
  const float b2r = b2[rown];
  float sum = 0.f;
  #pragma unroll
  for (int st = 0; st < 4; ++st) {
    const float z = pz[st][rown] + b2r;
    const float te = fast_exp2(2.8853901f * z);   // e^(2z); inf-safe: tanh->1
    sum += 1.f - 2.f * fast_rcp(te + 1.f);
  }
  const float cs_own = sum * 0.25f * (*scale_p);  // * dt * scale
  if (ls < 8) cshr[rib][ls] = cs_own;
  __syncthreads();

  // write u[row][64]: slice ls writes cols 4ls..4ls+3 as one 8B store
  bf16x4 o;
  #pragma unroll
  for (int j = 0; j < 4; ++j) {
    const int k = ls*4 + j;
    float val;
    if (k < 8) {
      val = cshr[rib][k];
    } else if (k < 44) {
      const int p = k - 8;
      int r = (p>=8)+(p>=15)+(p>=21)+(p>=26)+(p>=30)+(p>=33)+(p>=35);
      const int baser = r*8 - ((r*(r-1))>>1);
      const int s2 = r + p - baser;
      val = 0.5f * cshr[rib][r] * cshr[rib][s2];
    } else if (k == 44) {
      val = 1.f;
    } else {
      val = 0.f;
    }
    o[j] = (__bf16)val;
  }
  *(bf16x4*)(u + (size_t)row*KU + ls*4) = o;
}

// ---------------- K3: out[b][ij] = sum_k u[b][k] * Vt[ij][k]  (K=64) ----------------
// m-major grid; WG tile 64 rows x 256 cols, 4 waves side-by-side (each 64x64).
// B-rows permuted: frag b, lane lc <- col lc*4+b  => per-lane f32x4 stores.
__global__ __launch_bounds__(256) void out_gemm_kernel(
    const __bf16* __restrict__ u, const __bf16* __restrict__ Vt,
    float* __restrict__ out) {
  const int bid = blockIdx.x;
  const int mb = bid >> 4, nbq = bid & 15;
  const int tid = threadIdx.x;
  const int l = tid & 63, wv = tid >> 6;
  const int lc = l & 15, lg = l >> 4;
  const int m0 = mb*64;
  const int n0 = nbq*256 + wv*64;

  f32x4 acc[4][4];
  #pragma unroll
  for (int a = 0; a < 4; ++a)
    #pragma unroll
    for (int b = 0; b < 4; ++b) acc[a][b] = (f32x4)0.f;

  #pragma unroll
  for (int ks = 0; ks < 2; ++ks) {
    const int k0 = ks*32 + lg*8;
    bf16x8 aF[4], bF[4];
    #pragma unroll
    for (int a = 0; a < 4; ++a)
      aF[a] = *(const bf16x8*)(u + (size_t)(m0 + a*16 + lc)*KU + k0);
    #pragma unroll
    for (int b = 0; b < 4; ++b)
      bF[b] = *(const bf16x8*)(Vt + (size_t)(n0 + lc*4 + b)*KU + k0);
    #pragma unroll
    for (int a = 0; a < 4; ++a)
      #pragma unroll
      for (int b = 0; b < 4; ++b)
        acc[a][b] = MFMA16(aF[a], bF[b], acc[a][b]);
  }

  #pragma unroll
  for (int a = 0; a < 4; ++a)
    #pragma unroll
    for (int rg = 0; rg < 4; ++rg) {
      f32x4 o; o[0] = acc[a][0][rg]; o[1] = acc[a][1][rg];
      o[2] = acc[a][2][rg]; o[3] = acc[a][3][rg];
      *(f32x4*)(out + (size_t)(m0 + a*16 + lg*4 + rg)*4096 + n0 + lc*4) = o;
    }
}

extern "C" void kernel_launch(void* const* d_in, const int* in_sizes, int n_in,
                              void* d_out, int out_size, void* d_ws, size_t ws_size,
                              hipStream_t stream) {
  const float* xs    = (const float*)d_in[0];
  const float* xe    = (const float*)d_in[1];
  const float* W1    = (const float*)d_in[2];
  const float* b1    = (const float*)d_in[3];
  const float* W2    = (const float*)d_in[4];
  const float* b2    = (const float*)d_in[5];
  const float* gen   = (const float*)d_in[6];
  const float* scale = (const float*)d_in[7];

  char* ws = (char*)d_ws;
  __bf16* W1b = (__bf16*)ws;                                    // 512 KB
  __bf16* u   = (__bf16*)(ws + 512*1024);                       // 2 MB
  __bf16* Vt  = (__bf16*)(ws + 512*1024 + 2*1024*1024);         // 512 KB
  __bf16* w2p = (__bf16*)(ws + 512*1024 + 2*1024*1024 + 512*1024); // 8 KB

  // Gs/Ge scratch lives in d_out (32 MB of 268), fully overwritten by K3.
  char* outc = (char*)d_out;
  __bf16* Gsb = (__bf16*)outc;
  __bf16* Geb = (__bf16*)(outc + (size_t)16*1024*1024);

  prep_kernel<<<298, 256, 0, stream>>>(W1, W2, gen, W1b, w2p, Vt);
  mlp1_kernel<<<1024, 256, 0, stream>>>(xs, xe, W1b, b1, Gsb, Geb);
  coeff2_kernel<<<B_TOT/16, 256, 0, stream>>>(Gsb, Geb, w2p, b2, scale, u);
  out_gemm_kernel<<<256*16, 256, 0, stream>>>(u, Vt, (float*)d_out);
}

// Round 10
// 139.757 us; speedup vs baseline: 1.3425x; 1.0143x over previous
//
#include <hip/hip_runtime.h>

typedef __bf16 bf16x8 __attribute__((ext_vector_type(8)));
typedef __bf16 bf16x4 __attribute__((ext_vector_type(4)));
typedef float f32x4 __attribute__((ext_vector_type(4)));

#define B_TOT   16384
#define DM      512
#define NF      64
#define KU      64   // K for final GEMM: 8 G + 36 sym pairs + 1 eye + 19 zero

#define MFMA16(a,b,c) __builtin_amdgcn_mfma_f32_16x16x32_bf16(a,b,c,0,0,0)

static __device__ __forceinline__ void gload_lds16(const void* g, void* l) {
  __builtin_amdgcn_global_load_lds((const __attribute__((address_space(1))) char*)g,
                                   (__attribute__((address_space(3))) char*)l, 16, 0, 0);
}

static __device__ __forceinline__ float fast_exp2(float x) {
  return __builtin_amdgcn_exp2f(x);
}
static __device__ __forceinline__ float fast_rcp(float x) {
  return __builtin_amdgcn_rcpf(x);
}

static __device__ __forceinline__ bf16x8 cvt8(f32x4 lo, f32x4 hi) {
  bf16x8 r;
  r[0]=(__bf16)lo[0]; r[1]=(__bf16)lo[1]; r[2]=(__bf16)lo[2]; r[3]=(__bf16)lo[3];
  r[4]=(__bf16)hi[0]; r[5]=(__bf16)hi[1]; r[6]=(__bf16)hi[2]; r[7]=(__bf16)hi[3];
  return r;
}

// ---------------- prep: W1->bf16, w2p pack, Vt build ----------------
// grid 298: [0,256) W1 cvt; [256,258) w2p; [258,294) pair-product cols; [294,298) static cols
__global__ __launch_bounds__(256) void prep_kernel(const float* __restrict__ W1,
                                                   const float* __restrict__ W2,
                                                   const float* __restrict__ gen,
                                                   __bf16* __restrict__ W1b,
                                                   __bf16* __restrict__ w2p,
                                                   __bf16* __restrict__ Vt) {
  const int bid = blockIdx.x, tid = threadIdx.x;
  __shared__ float Ga[NF*NF];
  __shared__ float Gb[NF*NF];
  if (bid < 256) {
    const int i = (bid*256 + tid)*4;
    float4 v = *(const float4*)(W1 + i);
    bf16x4 o; o[0]=(__bf16)v.x; o[1]=(__bf16)v.y; o[2]=(__bf16)v.z; o[3]=(__bf16)v.w;
    *(bf16x4*)(W1b + i) = o;
  } else if (bid < 258) {
    const int n = (bid-256)*256 + tid;
    bf16x8 o;
    #pragma unroll
    for (int r = 0; r < 8; ++r) o[r] = (__bf16)W2[r*DM + n];
    *(bf16x8*)(w2p + n*8) = o;
  } else if (bid < 294) {
    // pair p -> (r,s), r<=s: col 8+p = G_r G_s + (r!=s) G_s G_r
    const int p = bid - 258;
    int r = (p>=8)+(p>=15)+(p>=21)+(p>=26)+(p>=30)+(p>=33)+(p>=35);
    const int baser = r*8 - ((r*(r-1))>>1);
    const int s = r + p - baser;
    for (int i = tid; i < NF*NF; i += 256) {
      Ga[i] = gen[r*NF*NF + i];
      Gb[i] = gen[s*NF*NF + i];
    }
    __syncthreads();
    const int i  = tid >> 2;
    const int j0 = (tid & 3) * 16;
    float acc[16];
    #pragma unroll
    for (int jj = 0; jj < 16; ++jj) acc[jj] = 0.f;
    for (int k = 0; k < NF; ++k) {
      float a = Ga[i*NF + k];
      #pragma unroll
      for (int jj = 0; jj < 16; ++jj) acc[jj] += a * Gb[k*NF + j0 + jj];
    }
    if (r != s) {
      for (int k = 0; k < NF; ++k) {
        float a = Gb[i*NF + k];
        #pragma unroll
        for (int jj = 0; jj < 16; ++jj) acc[jj] += a * Ga[k*NF + j0 + jj];
      }
    }
    #pragma unroll
    for (int jj = 0; jj < 16; ++jj)
      Vt[(size_t)(i*NF + j0 + jj)*KU + 8 + p] = (__bf16)acc[jj];
  } else {
    // static cols: 0..7 = G_r[ij]; 44 = eye; 45..63 = 0
    const int q = bid - 294;
    #pragma unroll
    for (int v = 0; v < 4; ++v) {
      const int ij = q*1024 + tid*4 + v;
      bf16x8 g8;
      #pragma unroll
      for (int r = 0; r < 8; ++r) g8[r] = (__bf16)gen[r*NF*NF + ij];
      __bf16* row = Vt + (size_t)ij*KU;
      *(bf16x8*)row = g8;
      const float eye = ((ij >> 6) == (ij & 63)) ? 1.f : 0.f;
      bf16x4 e4; e4[0] = (__bf16)eye; e4[1] = (__bf16)0.f; e4[2] = (__bf16)0.f; e4[3] = (__bf16)0.f;
      *(bf16x4*)(row + 44) = e4;
      bf16x8 z8;
      #pragma unroll
      for (int k = 0; k < 8; ++k) z8[k] = (__bf16)0.f;
      *(bf16x8*)(row + 48) = z8;
      *(bf16x8*)(row + 56) = z8;
    }
  }
}

// ---------------- K1a: Gs = xs@W1^T + b1, Ge = xe@W1^T + b1 ----------------
// NEW: WG tile 64m x 512n (FULL width), one mat per WG, grid 512 -> x is read
// from HBM exactly once (128 MB total; was ~3-4x due to n-tile re-reads).
// 4 waves: wave w owns n-strip [w*128, w*128+128); acc[4 mt][8 nt].
// LDS: As dbuf 2x8 KB (f32->reg->cvt->swizzled ds_write, e=row&7);
//      Bs single 64 KB = full W1 K-slice (gload_lds, src-swizzle e=(row>>3)&7,
//      L2-resident source). Per K-step: sync1 -> loadA early (HBM latency
//      hides under 64 MFMA) -> compute -> sync2 -> stageB+writeA.
// B-rows permuted: frag nt, lane lc <- n = w*128 + lc*8 + nt => per-lane
// bf16x8 G-stores, 256 B contiguous per (row, strip).
__global__ __launch_bounds__(256, 2) void mlp1_kernel(
    const float* __restrict__ xs, const float* __restrict__ xe,
    const __bf16* __restrict__ W1b, const float* __restrict__ b1,
    __bf16* __restrict__ Gsb, __bf16* __restrict__ Geb) {
  const int bid = blockIdx.x;
  const int mat = bid & 1;
  const int mtile = bid >> 1;
  const int m0 = mtile*64;
  const float* __restrict__ X = mat ? xe : xs;
  __bf16* __restrict__ G = mat ? Geb : Gsb;

  __shared__ __bf16 As[2][64*64];   // 2 x 8 KB; chunk c of row at slot c^(row&7)
  __shared__ __bf16 Bs[512*64];     // 64 KB;   chunk c of row at slot c^((row>>3)&7)

  const int tid = threadIdx.x;
  const int l = tid & 63, w = tid >> 6;
  const int lc = l & 15, lg = l >> 4;

  // ---- A staging map: thread -> row = tid>>2, 16 consecutive floats at col aq*16
  const int arow = tid >> 2;      // 0..63
  const int aq   = tid & 3;
  const float* asrc = X + (size_t)(m0 + arow)*DM + aq*16;

  auto stageB = [&](int k0) {
    #pragma unroll
    for (int c = 0; c < 16; ++c) {
      const int row = c*32 + (tid >> 3);
      const int sp = (tid & 7) ^ ((row >> 3) & 7);
      gload_lds16(W1b + (size_t)row*DM + k0 + sp*8,
                  (char*)Bs + c*4096 + tid*16);
    }
  };

  f32x4 ar[4];
  auto loadA = [&](int k0) {
    const float* p = asrc + k0;
    ar[0] = *(const f32x4*)(p);
    ar[1] = *(const f32x4*)(p + 4);
    ar[2] = *(const f32x4*)(p + 8);
    ar[3] = *(const f32x4*)(p + 12);
  };
  auto writeA = [&](int buf) {
    const int e = arow & 7;
    *(bf16x8*)(&As[buf][0] + arow*64 + (((aq*2    ) ^ e)*8)) = cvt8(ar[0], ar[1]);
    *(bf16x8*)(&As[buf][0] + arow*64 + (((aq*2 + 1) ^ e)*8)) = cvt8(ar[2], ar[3]);
  };

  f32x4 acc[4][8];
  #pragma unroll
  for (int a = 0; a < 4; ++a)
    #pragma unroll
    for (int b = 0; b < 8; ++b) acc[a][b] = (f32x4)0.f;

  // prologue: stage K-step 0
  loadA(0);
  stageB(0);
  writeA(0);

  for (int ks = 0; ks < 8; ++ks) {
    const int cb = ks & 1, nb = cb ^ 1;
    __syncthreads();                 // sync1: staging(ks) visible (vmcnt+lgkm)
    if (ks < 7) loadA((ks+1)*64);    // HBM loads issue early, drain after compute
    #pragma unroll
    for (int kk = 0; kk < 2; ++kk) {
      bf16x8 aF[4], bF[8];
      #pragma unroll
      for (int mt = 0; mt < 4; ++mt) {
        const int row = mt*16 + lc;
        const int sp = (kk*4 + lg) ^ (row & 7);
        aF[mt] = *(const bf16x8*)(&As[cb][0] + row*64 + sp*8);
      }
      #pragma unroll
      for (int nt = 0; nt < 8; ++nt) {
        const int row = w*128 + lc*8 + nt;
        const int sp = (kk*4 + lg) ^ ((row >> 3) & 7);
        bF[nt] = *(const bf16x8*)(Bs + row*64 + sp*8);
      }
      #pragma unroll
      for (int mt = 0; mt < 4; ++mt)
        #pragma unroll
        for (int nt = 0; nt < 8; ++nt)
          acc[mt][nt] = MFMA16(aF[mt], bF[nt], acc[mt][nt]);
    }
    if (ks < 7) {
      __syncthreads();               // sync2: all Bs/As reads for ks done
      stageB((ks+1)*64);             // Bs overwrite (L2-latency only exposed)
      writeA(nb);                    // A regs (drained during compute) -> other buf
    }
  }

  // epilogue: +b1, cvt bf16, per-lane bf16x8 stores (n = w*128 + lc*8 .. +8)
  f32x4 b1lo = *(const f32x4*)(b1 + w*128 + lc*8);
  f32x4 b1hi = *(const f32x4*)(b1 + w*128 + lc*8 + 4);
  #pragma unroll
  for (int mt = 0; mt < 4; ++mt) {
    #pragma unroll
    for (int rg = 0; rg < 4; ++rg) {
      const int m = m0 + mt*16 + lg*4 + rg;
      bf16x8 o;
      #pragma unroll
      for (int nt = 0; nt < 8; ++nt) {
        const float bb = (nt < 4) ? b1lo[nt] : b1hi[nt-4];
        o[nt] = (__bf16)(acc[mt][nt][rg] + bb);
      }
      *(bf16x8*)(G + (size_t)m*DM + w*128 + lc*8) = o;
    }
  }
}

// ---------------- K1b: coefficients ----------------
// per wave: 4 rows; lane = row_in_wave*16 + slice; slice covers n = {c*128 + slice*8 + i}
// coefficient fan-out goes through LDS (divergence-free reads; NO shfl in branches).
__global__ __launch_bounds__(256, 4) void coeff2_kernel(
    const __bf16* __restrict__ Gsb, const __bf16* __restrict__ Geb,
    const __bf16* __restrict__ w2p, const float* __restrict__ b2,
    const float* __restrict__ scale_p, __bf16* __restrict__ u) {
  const int tid = threadIdx.x;
  const int wv = tid >> 6, l = tid & 63;
  const int ls = l & 15;
  const int rib = wv*4 + (l >> 4);       // row in block, 0..15
  const int row = blockIdx.x*16 + rib;
  const size_t rb = (size_t)row * DM;

  __shared__ float cshr[16][8];

  float pz[4][8];
  #pragma unroll
  for (int st = 0; st < 4; ++st)
    #pragma unroll
    for (int r = 0; r < 8; ++r) pz[st][r] = 0.f;

  #pragma unroll
  for (int c = 0; c < 4; ++c) {
    const int nb = c*128 + ls*8;
    bf16x8 s8 = *(const bf16x8*)(Gsb + rb + nb);
    bf16x8 e8 = *(const bf16x8*)(Geb + rb + nb);
    #pragma unroll
    for (int i = 0; i < 8; ++i) {
      const float sv = (float)s8[i];
      const float dv = (float)e8[i] - sv;
      bf16x8 wv8 = *(const bf16x8*)(w2p + (size_t)(nb + i)*8);
      float w2f[8];
      #pragma unroll
      for (int r = 0; r < 8; ++r) w2f[r] = (float)wv8[r];
      #pragma unroll
      for (int st = 0; st < 4; ++st) {
        const float t = 0.125f + 0.25f*(float)st;
        const float mid = fmaf(t, dv, sv);
        // gelu ~= x * sigmoid(1.702 x); sigmoid via exp2 (hw v_exp_f32)
        const float g = mid * fast_rcp(1.f + fast_exp2(-2.4554669f * mid));
        #pragma unroll
        for (int r = 0; r < 8; ++r) pz[st][r] = fmaf(g, w2f[r], pz[st][r]);
      }
    }
  }

  // reduce over the 16 slices of this row
  #pragma unroll
  for (int st = 0; st < 4; ++st)
    #pragma unroll
    for (int r = 0; r < 8; ++r) {
      float v = pz[st][r];
      v += __shfl_xor(v, 1); v += __shfl_xor(v, 2);
      v += __shfl_xor(v, 4); v += __shfl_xor(v, 8);
      pz[st][r] = v;
    }

  // lane ls<8 finalizes r=ls for its row -> LDS
  const int rown = ls & 7;
  const float b2r = b2[rown];
  float sum = 0.f;
  #pragma unroll
  for (int st = 0; st < 4; ++st) {
    const float z = pz[st][rown] + b2r;
    const float te = fast_exp2(2.8853901f * z);   // e^(2z); inf-safe: tanh->1
    sum += 1.f - 2.f * fast_rcp(te + 1.f);
  }
  const float cs_own = sum * 0.25f * (*scale_p);  // * dt * scale
  if (ls < 8) cshr[rib][ls] = cs_own;
  __syncthreads();

  // write u[row][64]: slice ls writes cols 4ls..4ls+3 as one 8B store
  bf16x4 o;
  #pragma unroll
  for (int j = 0; j < 4; ++j) {
    const int k = ls*4 + j;
    float val;
    if (k < 8) {
      val = cshr[rib][k];
    } else if (k < 44) {
      const int p = k - 8;
      int r = (p>=8)+(p>=15)+(p>=21)+(p>=26)+(p>=30)+(p>=33)+(p>=35);
      const int baser = r*8 - ((r*(r-1))>>1);
      const int s2 = r + p - baser;
      val = 0.5f * cshr[rib][r] * cshr[rib][s2];
    } else if (k == 44) {
      val = 1.f;
    } else {
      val = 0.f;
    }
    o[j] = (__bf16)val;
  }
  *(bf16x4*)(u + (size_t)row*KU + ls*4) = o;
}

// ---------------- K3: out[b][ij] = sum_k u[b][k] * Vt[ij][k]  (K=64) ----------------
// m-major grid; WG tile 64 rows x 256 cols, 4 waves side-by-side (each 64x64).
// B-rows permuted: frag b, lane lc <- col lc*4+b  => per-lane f32x4 stores.
__global__ __launch_bounds__(256) void out_gemm_kernel(
    const __bf16* __restrict__ u, const __bf16* __restrict__ Vt,
    float* __restrict__ out) {
  const int bid = blockIdx.x;
  const int mb = bid >> 4, nbq = bid & 15;
  const int tid = threadIdx.x;
  const int l = tid & 63, wv = tid >> 6;
  const int lc = l & 15, lg = l >> 4;
  const int m0 = mb*64;
  const int n0 = nbq*256 + wv*64;

  f32x4 acc[4][4];
  #pragma unroll
  for (int a = 0; a < 4; ++a)
    #pragma unroll
    for (int b = 0; b < 4; ++b) acc[a][b] = (f32x4)0.f;

  #pragma unroll
  for (int ks = 0; ks < 2; ++ks) {
    const int k0 = ks*32 + lg*8;
    bf16x8 aF[4], bF[4];
    #pragma unroll
    for (int a = 0; a < 4; ++a)
      aF[a] = *(const bf16x8*)(u + (size_t)(m0 + a*16 + lc)*KU + k0);
    #pragma unroll
    for (int b = 0; b < 4; ++b)
      bF[b] = *(const bf16x8*)(Vt + (size_t)(n0 + lc*4 + b)*KU + k0);
    #pragma unroll
    for (int a = 0; a < 4; ++a)
      #pragma unroll
      for (int b = 0; b < 4; ++b)
        acc[a][b] = MFMA16(aF[a], bF[b], acc[a][b]);
  }

  #pragma unroll
  for (int a = 0; a < 4; ++a)
    #pragma unroll
    for (int rg = 0; rg < 4; ++rg) {
      f32x4 o; o[0] = acc[a][0][rg]; o[1] = acc[a][1][rg];
      o[2] = acc[a][2][rg]; o[3] = acc[a][3][rg];
      *(f32x4*)(out + (size_t)(m0 + a*16 + lg*4 + rg)*4096 + n0 + lc*4) = o;
    }
}

extern "C" void kernel_launch(void* const* d_in, const int* in_sizes, int n_in,
                              void* d_out, int out_size, void* d_ws, size_t ws_size,
                              hipStream_t stream) {
  const float* xs    = (const float*)d_in[0];
  const float* xe    = (const float*)d_in[1];
  const float* W1    = (const float*)d_in[2];
  const float* b1    = (const float*)d_in[3];
  const float* W2    = (const float*)d_in[4];
  const float* b2    = (const float*)d_in[5];
  const float* gen   = (const float*)d_in[6];
  const float* scale = (const float*)d_in[7];

  char* ws = (char*)d_ws;
  __bf16* W1b = (__bf16*)ws;                                    // 512 KB
  __bf16* u   = (__bf16*)(ws + 512*1024);                       // 2 MB
  __bf16* Vt  = (__bf16*)(ws + 512*1024 + 2*1024*1024);         // 512 KB
  __bf16* w2p = (__bf16*)(ws + 512*1024 + 2*1024*1024 + 512*1024); // 8 KB

  // Gs/Ge scratch lives in d_out (32 MB of 268), fully overwritten by K3.
  char* outc = (char*)d_out;
  __bf16* Gsb = (__bf16*)outc;
  __bf16* Geb = (__bf16*)(outc + (size_t)16*1024*1024);

  prep_kernel<<<298, 256, 0, stream>>>(W1, W2, gen, W1b, w2p, Vt);
  mlp1_kernel<<<512, 256, 0, stream>>>(xs, xe, W1b, b1, Gsb, Geb);
  coeff2_kernel<<<B_TOT/16, 256, 0, stream>>>(Gsb, Geb, w2p, b2, scale, u);
  out_gemm_kernel<<<256*16, 256, 0, stream>>>(u, Vt, (float*)d_out);
}